// Round 1
// baseline (283.172 us; speedup 1.0000x reference)
//
#include <hip/hip_runtime.h>

// DayAdapter: out[b,t,e] = softsign( x[b,t,:] @ W[day[b]] + bias[day[b]] )
// x: [64,1024,512] f32, day_ids: [64] i32, W: [24,512,512] f32, bias: [24,512] f32
//
// Round 3: async pipeline. Diagnosis: latency-bound (MfmaUtil 13.6%, HBM 40%,
// all pipes idle) because __syncthreads drained vmcnt(0) every K-step -> zero
// outstanding HBM requests during compute. Fix:
//   (a) Bs double-buffered, staged with global_load_lds issued one iteration
//       ahead, waited with COUNTED vmcnt(8) just before the tail barrier;
//   (b) A tile prefetched into registers one iteration ahead (T14 issue-early
//       / write-late), cvt+ds_write after barrier 1;
//   (c) raw s_barrier + hand-placed s_waitcnt (memory clobber) + sched_barrier
//       fences to pin VMEM issue order (the vmcnt counts rely on A(8),B(4),A'(8)).

#define DIM 512
#define SEQ 1024
#define NB 64
#define NDAYS 24
#define BM 128
#define BN 128
#define BK 64
#define NT (DIM / BK)  // 8 K-tiles
#define LDA (BK + 8)   // A row stride (bf16): +8 pad -> frag reads 2-way (free)

typedef __bf16 bf16x8 __attribute__((ext_vector_type(8)));
typedef __bf16 bf16x4 __attribute__((ext_vector_type(4)));
typedef float  f32x4  __attribute__((ext_vector_type(4)));

__device__ __forceinline__ void gll16(const void* g, void* l) {
    __builtin_amdgcn_global_load_lds(
        (const __attribute__((address_space(1))) unsigned int*)g,
        (__attribute__((address_space(3))) unsigned int*)l,
        16, 0, 0);
}

// ---- kernel 1: Wt[d][n][k] = bf16(W[d][k][n]) ----
__global__ __launch_bounds__(256)
void transpose_w_kernel(const float* __restrict__ W, __bf16* __restrict__ Wt) {
    __shared__ __bf16 T[32][33];
    const int d  = blockIdx.z;
    const int k0 = blockIdx.x * 32;
    const int n0 = blockIdx.y * 32;
    const int tx = threadIdx.x & 31;
    const int ty = threadIdx.x >> 5;   // 0..7
    const float* Wd = W + (size_t)d * DIM * DIM;
    #pragma unroll
    for (int i = 0; i < 4; ++i) {
        const int k = ty + i * 8;
        T[tx][k] = (__bf16)Wd[(size_t)(k0 + k) * DIM + n0 + tx];  // coalesced f32 read
    }
    __syncthreads();
    __bf16* Wtd = Wt + (size_t)d * DIM * DIM;
    #pragma unroll
    for (int i = 0; i < 4; ++i) {
        const int n = ty + i * 8;
        Wtd[(size_t)(n0 + n) * DIM + k0 + tx] = T[n][tx];         // coalesced bf16 write
    }
}

// ---- kernel 2: main GEMM + bias + softsign ----
__global__ __launch_bounds__(256, 3)
void day_adapter_kernel(const float* __restrict__ x,
                        const int*   __restrict__ day_ids,
                        const __bf16* __restrict__ Wt,
                        const float* __restrict__ bias,
                        float*       __restrict__ out)
{
    __shared__ __align__(16) __bf16 As[BM][LDA];     // 18432 B (single buffer)
    __shared__ __align__(16) __bf16 Bs[2][BN * BK];  // 2 x 16384 B, swizzled chunks

    // XCD swizzle: L = xcdslot(3b) | ntile(2b) | hi(6b); the 4 ntiles of one
    // (m,b) share L mod 8 -> same XCD under round-robin dispatch.
    const int L  = blockIdx.x;
    const int g  = (L >> 3) & 3;
    const int mb = (L & 7) | ((L >> 5) << 3);   // 0..511
    const int m  = mb & 7;
    const int bb = mb >> 3;

    const int n0  = g * BN;
    const int m0  = m * BM;
    const int tid = threadIdx.x;
    const int day = day_ids[bb];

    const float*  xb  = x   + (size_t)bb  * SEQ * DIM + (size_t)m0 * DIM;
    const __bf16* Wtb = Wt  + (size_t)day * DIM * DIM + (size_t)n0 * DIM;
    float*        ob  = out + (size_t)bb  * SEQ * DIM + (size_t)m0 * DIM + n0;

    const int wave = tid >> 6;
    const int lane = tid & 63;
    const int wm   = (wave >> 1) * 64;
    const int wn   = (wave & 1) * 64;
    const int l15  = lane & 15;
    const int quad = lane >> 4;          // 0..3
    const int kq   = quad * 8;

    // A staging map: 2 halves x 4 float4s; row = tid>>2 (+64), col = (tid&3)*4 + i*16
    const int a_row = tid >> 2;          // 0..63
    const int a_col = (tid & 3) * 4;

    f32x4 acc[4][4];
    const f32x4 zero = {0.f, 0.f, 0.f, 0.f};
    #pragma unroll
    for (int i = 0; i < 4; ++i)
        #pragma unroll
        for (int j = 0; j < 4; ++j) acc[i][j] = zero;

    float4 fA[8];   // in-flight A tile (f32), statically indexed -> stays in VGPRs

    // 8 x global_load_dwordx4 for tile k0 (A path), held in fA
    auto load_A = [&](int k0) {
        #pragma unroll
        for (int h = 0; h < 2; ++h)
            #pragma unroll
            for (int i = 0; i < 4; ++i)
                fA[h * 4 + i] = *(const float4*)(xb + (size_t)(a_row + h * 64) * DIM
                                                 + k0 + a_col + i * 16);
    };
    // cvt fA -> bf16, 8 x ds_write_b64 into As
    auto store_A = [&]() {
        #pragma unroll
        for (int h = 0; h < 2; ++h)
            #pragma unroll
            for (int i = 0; i < 4; ++i) {
                const float4 f = fA[h * 4 + i];
                bf16x4 v;
                v[0] = (__bf16)f.x; v[1] = (__bf16)f.y;
                v[2] = (__bf16)f.z; v[3] = (__bf16)f.w;
                *(bf16x4*)&As[a_row + h * 64][a_col + i * 16] = v;
            }
    };
    // 4 x global_load_lds dwordx4 into Bs[buf], XOR-swizzled 16B chunk placement
    auto stage_B = [&](int buf, int k0) {
        char* BsB = (char*)&Bs[buf][0];
        #pragma unroll
        for (int p = 0; p < 4; ++p) {
            const int s  = p * 256 + tid;
            const int n  = s >> 3;
            const int cp = s & 7;
            const int c  = cp ^ (n & 7);
            gll16(Wtb + (size_t)n * DIM + k0 + c * 8,
                  BsB + (size_t)(p * 256 + (tid & ~63)) * 16);
        }
    };

    // ---- prologue ----
    load_A(0);                                   // queue: A0(8)
    stage_B(0, 0);                               // queue: A0(8) B0(4)
    asm volatile("" ::: "memory");               // pin B0 before anything later
    __builtin_amdgcn_sched_barrier(0);
    store_A();                                   // compiler waits fA -> vmcnt(4)
    load_A(BK);                                  // queue: B0(4) A1(8)
    __builtin_amdgcn_sched_barrier(0);
    asm volatile("s_waitcnt vmcnt(8) lgkmcnt(0)" ::: "memory");  // B0 landed, A1 flying
    __builtin_amdgcn_s_barrier();                // As(k0), Bs[0] ready
    __builtin_amdgcn_sched_barrier(0);

    #pragma unroll
    for (int kk = 0; kk < NT; ++kk) {
        const int cur = kk & 1;
        // B prefetch for next tile: in flight across the whole compute phase.
        // Safe: Bs[cur^1] readers finished before the previous tail barrier.
        if (kk < NT - 1) stage_B(cur ^ 1, (kk + 1) * BK);

        #pragma unroll
        for (int ks = 0; ks < 2; ++ks) {
            bf16x8 af[4], bfr[4];
            #pragma unroll
            for (int i = 0; i < 4; ++i)
                af[i] = *(const bf16x8*)&As[wm + i * 16 + l15][ks * 32 + kq];
            #pragma unroll
            for (int j = 0; j < 4; ++j) {
                const int n  = wn + j * 16 + l15;
                const int c  = ks * 4 + quad;
                const int cp = c ^ (n & 7);
                bfr[j] = *(const bf16x8*)&Bs[cur][n * BK + cp * 8];
            }
            #pragma unroll
            for (int i = 0; i < 4; ++i)
                #pragma unroll
                for (int j = 0; j < 4; ++j)
                    acc[i][j] = __builtin_amdgcn_mfma_f32_16x16x32_bf16(
                        af[i], bfr[j], acc[i][j], 0, 0, 0);
        }

        if (kk < NT - 1) {
            __builtin_amdgcn_s_barrier();        // (1) all waves done reading As
            asm volatile("" ::: "memory");
            __builtin_amdgcn_sched_barrier(0);
            store_A();                           // A(kk+1): cvt + ds_write (compiler vmcnt(4))
            if (kk < NT - 2) load_A((kk + 2) * BK);  // queue: B(4) A''(8)
            __builtin_amdgcn_sched_barrier(0);
            if (kk < NT - 2)
                asm volatile("s_waitcnt vmcnt(8) lgkmcnt(0)" ::: "memory"); // B landed, A'' flying
            else
                asm volatile("s_waitcnt vmcnt(0) lgkmcnt(0)" ::: "memory"); // last: drain
            __builtin_amdgcn_s_barrier();        // (2) As(kk+1) + Bs[cur^1] ready
            __builtin_amdgcn_sched_barrier(0);
        }
    }

    // -- epilogue: bias + softsign --
    float bv[4];
    #pragma unroll
    for (int j = 0; j < 4; ++j)
        bv[j] = bias[(size_t)day * DIM + n0 + wn + j * 16 + l15];

    #pragma unroll
    for (int i = 0; i < 4; ++i) {
        const int rbase = wm + i * 16 + quad * 4;        // C/D: row = quad*4 + reg
        #pragma unroll
        for (int j = 0; j < 4; ++j) {
            const int col = wn + j * 16 + l15;           // C/D: col = lane&15
            #pragma unroll
            for (int r = 0; r < 4; ++r) {
                const float y = acc[i][j][r] + bv[j];
                ob[(size_t)(rbase + r) * DIM + col] = y / (1.0f + fabsf(y));
            }
        }
    }
}

extern "C" void kernel_launch(void* const* d_in, const int* in_sizes, int n_in,
                              void* d_out, int out_size, void* d_ws, size_t ws_size,
                              hipStream_t stream) {
    const float* x       = (const float*)d_in[0];
    const int*   day_ids = (const int*)  d_in[1];
    const float* W       = (const float*)d_in[2];
    const float* bias    = (const float*)d_in[3];
    float*       out     = (float*)d_out;
    __bf16*      Wt      = (__bf16*)d_ws;   // 24*512*512*2 = 12.58 MB

    dim3 tgrid(DIM / 32, DIM / 32, NDAYS);  // (16,16,24)
    transpose_w_kernel<<<tgrid, 256, 0, stream>>>(W, Wt);

    day_adapter_kernel<<<dim3(2048), 256, 0, stream>>>(x, day_ids, Wt, bias, out);
}